// Round 2
// baseline (287.253 us; speedup 1.0000x reference)
//
#include <hip/hip_runtime.h>
#include <math.h>

#define N_MEM   50000
#define P_TOT   4096
#define DDIM    256
#define HDIM    480
#define WDIM    640
#define SWEEPB  196           // mem-sweep blocks (50176 threads >= 50000)
#define COPYB   2048          // state-copy blocks (8/CU -> BW-bound, not latency-bound)
#define THR2    0.01f
#define EPSF    1e-8f

// ---- spatial hash grid over the 4096 QUERY points ----
// cell 0.6875m >= 2*RS so a mem point's radius query spans <=2 cells/dim (<=8 cells).
// RS=0.15 covers the 0.1m match radius with margin >> fp slop. Clamped-trunc cell
// mapping is monotone, so |px-mx|<=RS per-dim => cell(px) in [cell(mx-RS),cell(mx+RS)]
// regardless of clamping: every pair with d2<THR2 is tested => tested-min == true min
// whenever matched; unmatched decisions agree because tested-min >= true-min >= THR2.
#define GDIM    24
#define NCELL   13824         // 24^3
#define GORG    -8.25f
#define GINV    (1.0f/0.6875f)
#define GRS     0.15f
#define CPT     14            // cells per thread in prefix (1024*14 >= 13824)

typedef unsigned long long ull;

// monotone float->uint transform: a<b (float) <=> fsort(a)<fsort(b) (uint)
__device__ __forceinline__ unsigned fsort(float x) {
    unsigned b = __float_as_uint(x);
    return (b & 0x80000000u) ? ~b : (b | 0x80000000u);
}

__device__ __forceinline__ int cell1d(float x) {
    int c = (int)((x - GORG) * GINV);   // trunc; negatives trunc toward 0 then clamp
    return min(max(c, 0), GDIM - 1);
}

// ---------------- D1: fused pix2world + query-grid counting sort + inits (1 block) ----
// Replaces k_world + memset + hist + prefix + scatter (5 dispatches -> 1).
// 4096 points, 1024 threads: world transform (4 pts/thread, unrolled for load ILP),
// LDS histogram over 13824 cells, LDS prefix, scatter to global qidx/qstart.
// Also inits minkey[4096], minkey_inv, cos accumulator, election counter.
__global__ __launch_bounds__(1024) void k_build(const float* __restrict__ points,
                                                const float* __restrict__ depth,
                                                const float* __restrict__ pose,
                                                const float* __restrict__ Kmat,
                                                float4* __restrict__ pts_out,
                                                int* __restrict__ flags_out,
                                                ull* __restrict__ minkey,
                                                int* __restrict__ qstart,
                                                int* __restrict__ qidx,
                                                ull* __restrict__ minkey_inv,
                                                float* __restrict__ cos_acc,
                                                unsigned* __restrict__ done_cnt)
{
    __shared__ int cnt[NCELL];      // 55296 B
    __shared__ int bsum[1024];
    int t = threadIdx.x;
    for (int c = t; c < NCELL; c += 1024) cnt[c] = 0;
    if (t == 0) { *minkey_inv = 0xFFFFFFFFFFFFFFFFULL; *cos_acc = 0.f; *done_cnt = 0u; }
    for (int k = t; k < P_TOT; k += 1024) minkey[k] = 0xFFFFFFFFFFFFFFFFULL;
    __syncthreads();

    int cells[4];
    #pragma unroll
    for (int i = 0; i < 4; ++i) {
        int p = i * 1024 + t;               // coalesced across threads
        int b = p >> 9;
        const float* K = Kmat + b * 9;
        float a00=K[0],a01=K[1],a02=K[2],a10=K[3],a11=K[4],a12=K[5],a20=K[6],a21=K[7],a22=K[8];
        float det = a00*(a11*a22-a12*a21) - a01*(a10*a22-a12*a20) + a02*(a10*a21-a11*a20);
        float id = 1.0f/det;
        float i00=(a11*a22-a12*a21)*id, i01=(a02*a21-a01*a22)*id, i02=(a01*a12-a02*a11)*id;
        float i10=(a12*a20-a10*a22)*id, i11=(a00*a22-a02*a20)*id, i12=(a02*a10-a00*a12)*id;
        float i20=(a10*a21-a11*a20)*id, i21=(a01*a20-a00*a21)*id, i22=(a00*a11-a01*a10)*id;

        float u = points[p*2+0], v = points[p*2+1];
        float uc = fminf(fmaxf(u, 0.f), (float)WDIM - 1.001f);
        float vc = fminf(fmaxf(v, 0.f), (float)HDIM - 1.001f);
        float u0 = floorf(uc), v0 = floorf(vc);
        float du = uc - u0, dv = vc - v0;
        int u0i = (int)u0, v0i = (int)v0;
        const float* dm = depth + (size_t)b * HDIM * WDIM;
        float d00 = dm[v0i*WDIM + u0i];
        float d01 = dm[v0i*WDIM + u0i + 1];
        float d10 = dm[(v0i+1)*WDIM + u0i];
        float d11 = dm[(v0i+1)*WDIM + u0i + 1];
        float d = d00*(1.f-du)*(1.f-dv) + d01*du*(1.f-dv) + d10*(1.f-du)*dv + d11*du*dv;

        float cx = (i00*u + i01*v + i02) * d;
        float cy = (i10*u + i11*v + i12) * d;
        float cz = (i20*u + i21*v + i22) * d;
        const float* T = pose + b * 12;
        float wx = T[0]*cx + T[1]*cy + T[2]*cz  + T[3];
        float wy = T[4]*cx + T[5]*cy + T[6]*cz  + T[7];
        float wz = T[8]*cx + T[9]*cy + T[10]*cz + T[11];
        int val = (d > 0.f) && isfinite(wx) && isfinite(wy) && isfinite(wz);
        float px = val ? wx : 1e6f;
        float py = val ? wy : 1e6f;
        float pz = val ? wz : 1e6f;
        float pp = px*px + py*py + pz*pz;   // same arith chain as prior passing kernels
        pts_out[p] = make_float4(px, py, pz, pp);
        flags_out[p] = val;
        int c = -1;
        if (val) {
            c = (cell1d(pz) * GDIM + cell1d(py)) * GDIM + cell1d(px);
            atomicAdd(&cnt[c], 1);
        }
        cells[i] = c;                        // static index (unrolled) -> stays in regs
    }
    __syncthreads();

    // exclusive prefix over 13824 cells
    int base = t * CPT;
    int loc[CPT];
    int sum = 0;
    #pragma unroll
    for (int i = 0; i < CPT; ++i) {
        int idx = base + i;
        int cv = (idx < NCELL) ? cnt[idx] : 0;
        loc[i] = sum; sum += cv;
    }
    bsum[t] = sum;
    __syncthreads();
    for (int off = 1; off < 1024; off <<= 1) {
        int a = bsum[t];
        int bb = (t >= off) ? bsum[t - off] : 0;
        __syncthreads();
        bsum[t] = a + bb;
        __syncthreads();
    }
    int ex = bsum[t] - sum;
    #pragma unroll
    for (int i = 0; i < CPT; ++i) {
        int idx = base + i;
        if (idx < NCELL) { int s0 = ex + loc[i]; qstart[idx] = s0; cnt[idx] = s0; }
    }
    if (t == 1023) qstart[NCELL] = bsum[1023];   // total valid points
    __syncthreads();

    // scatter (cnt[] now = cursors)
    #pragma unroll
    for (int i = 0; i < 4; ++i) {
        if (cells[i] >= 0) {
            int p = i * 1024 + t;
            int pos = atomicAdd(&cnt[cells[i]], 1);
            qidx[pos] = p;
        }
    }
}

// ---------------- D2: mem-side sweep (atomicMin candidates) + state copy ----------------
// blocks [0,SWEEPB): 1 thread per mem point j: test query points in j's <=8 neighbor
//   cells (packed-key atomicMin => exact (d,j) lexicographic min over tested superset
//   of all sub-threshold pairs), plus block-reduced global argmin for the shared
//   invalid-point position (1e6,1e6,1e6) -> minkey_inv.
// blocks [SWEEPB, SWEEPB+COPYB): grid-stride copy of mem state -> out (the BW floor).
__global__ __launch_bounds__(256) void k_main(const float* __restrict__ mem_pts,
                                              const float* __restrict__ mem_desc,
                                              const float4* __restrict__ pts,
                                              const int* __restrict__ qstart,
                                              const int* __restrict__ qidx,
                                              ull* __restrict__ minkey,
                                              ull* __restrict__ minkey_inv,
                                              float* __restrict__ out_pts,
                                              float* __restrict__ out_desc)
{
    __shared__ ull sred[4];
    int bid = blockIdx.x;
    int t = threadIdx.x;
    if (bid < SWEEPB) {
        int j = bid * 256 + t;
        ull ikey = 0xFFFFFFFFFFFFFFFFULL;
        if (j < N_MEM) {
            float mx = mem_pts[j*3+0], my = mem_pts[j*3+1], mz = mem_pts[j*3+2];
            float mm = mx*mx + my*my + mz*mz;       // same expr as prior passing kernels
            // invalid-point key (all invalid query points sit at exactly (1e6)^3)
            float px = 1e6f;
            float pp  = px*px + px*px + px*px;
            float dot = px*mx + px*my + px*mz;
            float dinv = pp - 2.f*dot + mm;
            ikey = ((ull)fsort(dinv) << 32) | (unsigned)j;
            // neighbor-cell sweep over query grid
            int cx0 = cell1d(mx - GRS), cx1 = cell1d(mx + GRS);
            int cy0 = cell1d(my - GRS), cy1 = cell1d(my + GRS);
            int cz0 = cell1d(mz - GRS), cz1 = cell1d(mz + GRS);
            for (int zz = cz0; zz <= cz1; ++zz)
                for (int yy = cy0; yy <= cy1; ++yy) {
                    int rowc = (zz * GDIM + yy) * GDIM;
                    for (int xx = cx0; xx <= cx1; ++xx) {
                        int cell = rowc + xx;
                        int s0 = qstart[cell], s1 = qstart[cell + 1];
                        for (int k = s0; k < s1; ++k) {
                            int p = qidx[k];
                            float4 P = pts[p];
                            float dotq = P.x*mx + P.y*my + P.z*mz;
                            float dd2 = P.w - 2.f*dotq + mm;   // fp form identical to ref-passing kernels
                            atomicMin(&minkey[p], ((ull)fsort(dd2) << 32) | (unsigned)j);
                        }
                    }
                }
        }
        for (int off = 32; off; off >>= 1) {
            ull o = __shfl_xor(ikey, off);
            ikey = o < ikey ? o : ikey;
        }
        if ((t & 63) == 0) sred[t >> 6] = ikey;
        __syncthreads();
        if (t == 0) {
            ull a = sred[0] < sred[1] ? sred[0] : sred[1];
            ull b = sred[2] < sred[3] ? sred[2] : sred[3];
            ull m = a < b ? a : b;
            atomicMin(minkey_inv, m);
        }
    } else {
        const long tid = (long)(bid - SWEEPB) * 256 + t;
        const long stride = (long)COPYB * 256;
        const float2* ds = (const float2*)mem_desc;
        float2* dd = (float2*)out_desc;                 // 8B-aligned (offset 600008 B)
        const long ND2 = (long)N_MEM * DDIM / 2;        // 6.4e6 float2
        long k = tid * 4;
        const long stride4 = stride * 4;
        for (; k + 3 < ND2; k += stride4) {             // 4-deep unroll: loads in flight
            float2 a0 = ds[k+0], a1 = ds[k+1], a2 = ds[k+2], a3 = ds[k+3];
            dd[k+0] = a0; dd[k+1] = a1; dd[k+2] = a2; dd[k+3] = a3;
        }
        for (; k < ND2; ++k) dd[k] = ds[k];
        const float2* ps = (const float2*)mem_pts;
        float2* pd = (float2*)out_pts;
        for (long i = tid; i < (long)N_MEM * 3 / 2; i += stride) pd[i] = ps[i];
    }
}

// ---------------- D3: decode keys, scan unmatched -> widx, winner, n_match ----------------
// 1024 threads x 4 points each. Invalid points take the shared global-argmin key.
// Also emits nv (valid count) and n_unmatched for the loss election in D4.
__global__ __launch_bounds__(1024) void k_scan(const ull* __restrict__ minkey,
                                               int* __restrict__ flags,
                                               const int* __restrict__ next_ptr,
                                               const ull* __restrict__ minkey_inv,
                                               int* __restrict__ widx,
                                               int* __restrict__ winner,
                                               float* __restrict__ dout,
                                               float* __restrict__ scan_out)
{
    __shared__ int su[1024];
    __shared__ int smc[1024];
    int t = threadIdx.x;
    int base = t * 4;
    const ull thr_key = ((ull)fsort(THR2)) << 32;   // key<thr_key <=> d<THR2 exactly
    ull inv = *minkey_inv;
    int um[4], iv[4], wvv[4];
    int usum = 0, msum = 0;
    #pragma unroll
    for (int k = 0; k < 4; k++) {
        int v = flags[base + k] & 1;
        ull key = v ? minkey[base + k] : inv;
        int m = (key < thr_key) && v;
        int u = (!m) && v;
        iv[k] = (int)(key & 0xffffffffULL);
        um[k] = u; usum += u; msum += m;
        flags[base + k] = v | (m << 1) | (u << 2);
    }
    su[t] = usum; smc[t] = msum;
    __syncthreads();
    for (int off = 1; off < 1024; off <<= 1) {
        int a = su[t], b = (t >= off) ? su[t - off] : 0;
        int c = smc[t], d = (t >= off) ? smc[t - off] : 0;
        __syncthreads();
        su[t] = a + b; smc[t] = c + d;
        __syncthreads();
    }
    int excl = su[t] - usum;
    int np_ = *next_ptr;
    int run = excl;
    #pragma unroll
    for (int k = 0; k < 4; k++) {
        int wv;
        if (um[k]) { run += 1; wv = (np_ + run - 1) % N_MEM; }
        else       { wv = iv[k]; }
        widx[base + k] = wv;
        wvv[k] = wv;
        winner[wv] = -1;                   // init touched slots (racing -1 stores benign)
    }
    __syncthreads();
    #pragma unroll
    for (int k = 0; k < 4; k++)
        atomicMax(&winner[wvv[k]], base + k);   // last-write-wins = max p per slot
    if (t == 1023) {
        dout[1]     = (float)smc[1023];                 // n_match
        scan_out[0] = (float)(smc[1023] + su[1023]);    // nv = matched + unmatched valid
        scan_out[1] = (float)su[1023];                  // n_unmatched valid (each cos=1)
    }
}

// ---------------- D4: fused scatter + matched-cos accumulation + loss election --------
// sum(cos*valid) = sum_matched(cosv) + n_unmatched. Matched blocks atomicAdd cosv;
// the last block to finish (election counter) computes the final loss -> no k_final.
__global__ __launch_bounds__(256) void k_scatloss(const int* __restrict__ widx,
                                                  const int* __restrict__ flags,
                                                  const int* __restrict__ winner,
                                                  const float* __restrict__ desc,
                                                  const float4* __restrict__ pts,
                                                  const float* __restrict__ mem_pts,
                                                  const float* __restrict__ mem_desc,
                                                  float* __restrict__ out_pts,
                                                  float* __restrict__ out_desc,
                                                  const float* __restrict__ scan_out,
                                                  float* __restrict__ cos_acc,
                                                  unsigned* __restrict__ done_cnt,
                                                  float* __restrict__ dout)
{
    __shared__ float red[16];
    int p = blockIdx.x;
    int t = threadIdx.x;
    int f = flags[p];
    int m = (f >> 1) & 1, u = (f >> 2) & 1;
    int wi = widx[p];
    int win = (winner[wi] == p);
    if (m || win) {
        float dsg = desc[p * DDIM + t];
        float old = mem_desc[(long)wi * DDIM + t];   // for matched, wi == idx[p]
        float val;
        if (m) {
            float up = old * 0.5f + dsg * 0.5f;
            float sdd = dsg * dsg, smm2 = old * old, sdm = dsg * old, suu = up * up;
            for (int off = 32; off; off >>= 1) {
                sdd  += __shfl_xor(sdd,  off);
                smm2 += __shfl_xor(smm2, off);
                sdm  += __shfl_xor(sdm,  off);
                suu  += __shfl_xor(suu,  off);
            }
            int w = t >> 6;
            if ((t & 63) == 0) { red[w] = sdd; red[4+w] = smm2; red[8+w] = sdm; red[12+w] = suu; }
            __syncthreads();
            float dd  = red[0] + red[1] + red[2] + red[3];
            float mm2 = red[4] + red[5] + red[6] + red[7];
            float dm  = red[8] + red[9] + red[10] + red[11];
            float uu  = red[12] + red[13] + red[14] + red[15];
            float cosv = dm / (fmaxf(sqrtf(dd), EPSF) * fmaxf(sqrtf(mm2), EPSF));
            val = up / (sqrtf(uu) + EPSF);
            if (t == 0) atomicAdd(cos_acc, cosv);   // matched contribution (win or not)
        } else {
            val = u ? dsg : old;                // invalid winner rewrites old value (np semantics)
        }
        if (win) {
            out_desc[(long)wi * DDIM + t] = val;
            if (t == 0) {
                float px, py, pz;
                if (u) { float4 P = pts[p]; px = P.x; py = P.y; pz = P.z; }
                else   { px = mem_pts[wi*3]; py = mem_pts[wi*3+1]; pz = mem_pts[wi*3+2]; }
                out_pts[wi*3+0] = px; out_pts[wi*3+1] = py; out_pts[wi*3+2] = pz;
            }
        }
    }
    if (t == 0) {
        __threadfence();                              // order cos add before done add
        unsigned old_d = atomicAdd(done_cnt, 1u);
        if (old_d == P_TOT - 1) {                     // last block: all adds visible
            float ca = atomicAdd(cos_acc, 0.f);       // coherent read via RMW
            float nv = fmaxf(scan_out[0], 1.f);
            dout[0] = 1.f - (ca + scan_out[1]) / nv;
        }
    }
}

extern "C" void kernel_launch(void* const* d_in, const int* in_sizes, int n_in,
                              void* d_out, int out_size, void* d_ws, size_t ws_size,
                              hipStream_t stream)
{
    const float* points   = (const float*)d_in[0];
    const float* depth    = (const float*)d_in[1];
    const float* pose     = (const float*)d_in[2];
    const float* Kmat     = (const float*)d_in[3];
    const float* desc     = (const float*)d_in[4];
    const float* mem_pts  = (const float*)d_in[5];
    const float* mem_desc = (const float*)d_in[6];
    const int*   next_ptr = (const int*)d_in[7];

    float* out      = (float*)d_out;
    float* out_pts  = out + 2;
    float* out_desc = out + 2 + (long)N_MEM * 3;

    char* ws = (char*)d_ws;
    float4* pts_ws    = (float4*)(ws);               //  65536 B
    int* flags_ws     = (int*)(ws + 65536);          //  16384 -> 81920
    int* widx_ws      = (int*)(ws + 81920);          //  16384 -> 98304
    int* winner_ws    = (int*)(ws + 98304);          // 200000 -> 298304
    ull* minkey_ws    = (ull*)(ws + 298304);         //  32768 -> 331072 (8B aligned)
    int* qstart_ws    = (int*)(ws + 331072);         //  55300 -> 386372
    int* qidx_ws      = (int*)(ws + 386372);         //  16384 -> 402756
    ull* minkey_inv   = (ull*)(ws + 402760);         //      8 -> 402768 (8B aligned)
    float* scan_out   = (float*)(ws + 402768);       //      8 -> 402776
    float* cos_acc    = (float*)(ws + 402776);       //      4 -> 402780
    unsigned* done_ws = (unsigned*)(ws + 402780);    //      4 -> 402784

    k_build   <<<1, 1024, 0, stream>>>(points, depth, pose, Kmat,
                                       pts_ws, flags_ws, minkey_ws,
                                       qstart_ws, qidx_ws, minkey_inv, cos_acc, done_ws);
    k_main    <<<SWEEPB + COPYB, 256, 0, stream>>>(mem_pts, mem_desc, pts_ws,
                                                   qstart_ws, qidx_ws, minkey_ws, minkey_inv,
                                                   out_pts, out_desc);
    k_scan    <<<1, 1024, 0, stream>>>(minkey_ws, flags_ws, next_ptr, minkey_inv,
                                       widx_ws, winner_ws, out, scan_out);
    k_scatloss<<<P_TOT, 256, 0, stream>>>(widx_ws, flags_ws, winner_ws, desc, pts_ws,
                                          mem_pts, mem_desc, out_pts, out_desc,
                                          scan_out, cos_acc, done_ws, out);
}

// Round 4
// 203.291 us; speedup vs baseline: 1.4130x; 1.4130x over previous
//
#include <hip/hip_runtime.h>
#include <math.h>

#define N_MEM   50000
#define P_TOT   4096
#define DDIM    256
#define HDIM    480
#define WDIM    640
#define SWEEPB  196           // mem-sweep blocks (50176 threads >= 50000)
#define COPYB   2048          // state-copy blocks (8/CU -> BW-bound, not latency-bound)
#define THR2    0.01f
#define EPSF    1e-8f

// ---- spatial hash grid over the 4096 QUERY points ----
// cell 0.6875m >= 2*RS so a mem point's radius query spans <=2 cells/dim (<=8 cells).
// RS=0.15 covers the 0.1m match radius with margin >> fp slop. Clamped-trunc cell
// mapping is monotone, so |px-mx|<=RS per-dim => cell(px) in [cell(mx-RS),cell(mx+RS)]
// regardless of clamping: every pair with d2<THR2 is tested => tested-min == true min
// whenever matched; unmatched decisions agree because tested-min >= true-min >= THR2.
#define GDIM    24
#define NCELL   13824         // 24^3
#define GORG    -8.25f
#define GINV    (1.0f/0.6875f)
#define GRS     0.15f
#define CPT     14            // cells per thread in prefix (1024*14 >= 13824)

typedef unsigned long long ull;

// monotone float->uint transform: a<b (float) <=> fsort(a)<fsort(b) (uint)
__device__ __forceinline__ unsigned fsort(float x) {
    unsigned b = __float_as_uint(x);
    return (b & 0x80000000u) ? ~b : (b | 0x80000000u);
}

__device__ __forceinline__ int cell1d(float x) {
    int c = (int)((x - GORG) * GINV);   // trunc; negatives trunc toward 0 then clamp
    return min(max(c, 0), GDIM - 1);
}

// ---------------- D1: fused pix2world + query-grid counting sort + inits (1 block) ----
__global__ __launch_bounds__(1024) void k_build(const float* __restrict__ points,
                                                const float* __restrict__ depth,
                                                const float* __restrict__ pose,
                                                const float* __restrict__ Kmat,
                                                float4* __restrict__ pts_out,
                                                int* __restrict__ flags_out,
                                                ull* __restrict__ minkey,
                                                int* __restrict__ qstart,
                                                int* __restrict__ qidx,
                                                ull* __restrict__ minkey_inv,
                                                float* __restrict__ cos_acc)
{
    __shared__ int cnt[NCELL];      // 55296 B
    __shared__ int bsum[1024];
    int t = threadIdx.x;
    for (int c = t; c < NCELL; c += 1024) cnt[c] = 0;
    if (t == 0) { *minkey_inv = 0xFFFFFFFFFFFFFFFFULL; *cos_acc = 0.f; }
    for (int k = t; k < P_TOT; k += 1024) minkey[k] = 0xFFFFFFFFFFFFFFFFULL;
    __syncthreads();

    int cells[4];
    #pragma unroll
    for (int i = 0; i < 4; ++i) {
        int p = i * 1024 + t;               // coalesced across threads
        int b = p >> 9;
        const float* K = Kmat + b * 9;
        float a00=K[0],a01=K[1],a02=K[2],a10=K[3],a11=K[4],a12=K[5],a20=K[6],a21=K[7],a22=K[8];
        float det = a00*(a11*a22-a12*a21) - a01*(a10*a22-a12*a20) + a02*(a10*a21-a11*a20);
        float id = 1.0f/det;
        float i00=(a11*a22-a12*a21)*id, i01=(a02*a21-a01*a22)*id, i02=(a01*a12-a02*a11)*id;
        float i10=(a12*a20-a10*a22)*id, i11=(a00*a22-a02*a20)*id, i12=(a02*a10-a00*a12)*id;
        float i20=(a10*a21-a11*a20)*id, i21=(a01*a20-a00*a21)*id, i22=(a00*a11-a01*a10)*id;

        float u = points[p*2+0], v = points[p*2+1];
        float uc = fminf(fmaxf(u, 0.f), (float)WDIM - 1.001f);
        float vc = fminf(fmaxf(v, 0.f), (float)HDIM - 1.001f);
        float u0 = floorf(uc), v0 = floorf(vc);
        float du = uc - u0, dv = vc - v0;
        int u0i = (int)u0, v0i = (int)v0;
        const float* dm = depth + (size_t)b * HDIM * WDIM;
        float d00 = dm[v0i*WDIM + u0i];
        float d01 = dm[v0i*WDIM + u0i + 1];
        float d10 = dm[(v0i+1)*WDIM + u0i];
        float d11 = dm[(v0i+1)*WDIM + u0i + 1];
        float d = d00*(1.f-du)*(1.f-dv) + d01*du*(1.f-dv) + d10*(1.f-du)*dv + d11*du*dv;

        float cx = (i00*u + i01*v + i02) * d;
        float cy = (i10*u + i11*v + i12) * d;
        float cz = (i20*u + i21*v + i22) * d;
        const float* T = pose + b * 12;
        float wx = T[0]*cx + T[1]*cy + T[2]*cz  + T[3];
        float wy = T[4]*cx + T[5]*cy + T[6]*cz  + T[7];
        float wz = T[8]*cx + T[9]*cy + T[10]*cz + T[11];
        int val = (d > 0.f) && isfinite(wx) && isfinite(wy) && isfinite(wz);
        float px = val ? wx : 1e6f;
        float py = val ? wy : 1e6f;
        float pz = val ? wz : 1e6f;
        float pp = px*px + py*py + pz*pz;   // same arith chain as prior passing kernels
        pts_out[p] = make_float4(px, py, pz, pp);
        flags_out[p] = val;
        int c = -1;
        if (val) {
            c = (cell1d(pz) * GDIM + cell1d(py)) * GDIM + cell1d(px);
            atomicAdd(&cnt[c], 1);
        }
        cells[i] = c;                        // static index (unrolled) -> stays in regs
    }
    __syncthreads();

    // exclusive prefix over 13824 cells
    int base = t * CPT;
    int loc[CPT];
    int sum = 0;
    #pragma unroll
    for (int i = 0; i < CPT; ++i) {
        int idx = base + i;
        int cv = (idx < NCELL) ? cnt[idx] : 0;
        loc[i] = sum; sum += cv;
    }
    bsum[t] = sum;
    __syncthreads();
    for (int off = 1; off < 1024; off <<= 1) {
        int a = bsum[t];
        int bb = (t >= off) ? bsum[t - off] : 0;
        __syncthreads();
        bsum[t] = a + bb;
        __syncthreads();
    }
    int ex = bsum[t] - sum;
    #pragma unroll
    for (int i = 0; i < CPT; ++i) {
        int idx = base + i;
        if (idx < NCELL) { int s0 = ex + loc[i]; qstart[idx] = s0; cnt[idx] = s0; }
    }
    if (t == 1023) qstart[NCELL] = bsum[1023];   // total valid points
    __syncthreads();

    // scatter (cnt[] now = cursors)
    #pragma unroll
    for (int i = 0; i < 4; ++i) {
        if (cells[i] >= 0) {
            int p = i * 1024 + t;
            int pos = atomicAdd(&cnt[cells[i]], 1);
            qidx[pos] = p;
        }
    }
}

// ---------------- D2: mem-side sweep (atomicMin candidates) + state copy ----------------
__global__ __launch_bounds__(256) void k_main(const float* __restrict__ mem_pts,
                                              const float* __restrict__ mem_desc,
                                              const float4* __restrict__ pts,
                                              const int* __restrict__ qstart,
                                              const int* __restrict__ qidx,
                                              ull* __restrict__ minkey,
                                              ull* __restrict__ minkey_inv,
                                              float* __restrict__ out_pts,
                                              float* __restrict__ out_desc)
{
    __shared__ ull sred[4];
    int bid = blockIdx.x;
    int t = threadIdx.x;
    if (bid < SWEEPB) {
        int j = bid * 256 + t;
        ull ikey = 0xFFFFFFFFFFFFFFFFULL;
        if (j < N_MEM) {
            float mx = mem_pts[j*3+0], my = mem_pts[j*3+1], mz = mem_pts[j*3+2];
            float mm = mx*mx + my*my + mz*mz;       // same expr as prior passing kernels
            // invalid-point key (all invalid query points sit at exactly (1e6)^3)
            float px = 1e6f;
            float pp  = px*px + px*px + px*px;
            float dot = px*mx + px*my + px*mz;
            float dinv = pp - 2.f*dot + mm;
            ikey = ((ull)fsort(dinv) << 32) | (unsigned)j;
            // neighbor-cell sweep over query grid
            int cx0 = cell1d(mx - GRS), cx1 = cell1d(mx + GRS);
            int cy0 = cell1d(my - GRS), cy1 = cell1d(my + GRS);
            int cz0 = cell1d(mz - GRS), cz1 = cell1d(mz + GRS);
            for (int zz = cz0; zz <= cz1; ++zz)
                for (int yy = cy0; yy <= cy1; ++yy) {
                    int rowc = (zz * GDIM + yy) * GDIM;
                    for (int xx = cx0; xx <= cx1; ++xx) {
                        int cell = rowc + xx;
                        int s0 = qstart[cell], s1 = qstart[cell + 1];
                        for (int k = s0; k < s1; ++k) {
                            int p = qidx[k];
                            float4 P = pts[p];
                            float dotq = P.x*mx + P.y*my + P.z*mz;
                            float dd2 = P.w - 2.f*dotq + mm;   // fp form identical to ref-passing kernels
                            atomicMin(&minkey[p], ((ull)fsort(dd2) << 32) | (unsigned)j);
                        }
                    }
                }
        }
        for (int off = 32; off; off >>= 1) {
            ull o = __shfl_xor(ikey, off);
            ikey = o < ikey ? o : ikey;
        }
        if ((t & 63) == 0) sred[t >> 6] = ikey;
        __syncthreads();
        if (t == 0) {
            ull a = sred[0] < sred[1] ? sred[0] : sred[1];
            ull b = sred[2] < sred[3] ? sred[2] : sred[3];
            ull m = a < b ? a : b;
            atomicMin(minkey_inv, m);
        }
    } else {
        const long tid = (long)(bid - SWEEPB) * 256 + t;
        const long stride = (long)COPYB * 256;
        const float2* ds = (const float2*)mem_desc;
        float2* dd = (float2*)out_desc;                 // 8B-aligned (offset 600008 B)
        const long ND2 = (long)N_MEM * DDIM / 2;        // 6.4e6 float2
        long k = tid * 4;
        const long stride4 = stride * 4;
        for (; k + 3 < ND2; k += stride4) {             // 4-deep unroll: loads in flight
            float2 a0 = ds[k+0], a1 = ds[k+1], a2 = ds[k+2], a3 = ds[k+3];
            dd[k+0] = a0; dd[k+1] = a1; dd[k+2] = a2; dd[k+3] = a3;
        }
        for (; k < ND2; ++k) dd[k] = ds[k];
        const float2* ps = (const float2*)mem_pts;
        float2* pd = (float2*)out_pts;
        for (long i = tid; i < (long)N_MEM * 3 / 2; i += stride) pd[i] = ps[i];
    }
}

// ---------------- D3: decode keys, scan unmatched -> widx, winner, n_match ----------------
__global__ __launch_bounds__(1024) void k_scan(const ull* __restrict__ minkey,
                                               int* __restrict__ flags,
                                               const int* __restrict__ next_ptr,
                                               const ull* __restrict__ minkey_inv,
                                               int* __restrict__ widx,
                                               int* __restrict__ winner,
                                               float* __restrict__ dout,
                                               float* __restrict__ scan_out)
{
    __shared__ int su[1024];
    __shared__ int smc[1024];
    int t = threadIdx.x;
    int base = t * 4;
    const ull thr_key = ((ull)fsort(THR2)) << 32;   // key<thr_key <=> d<THR2 exactly
    ull inv = *minkey_inv;
    int um[4], iv[4], wvv[4];
    int usum = 0, msum = 0;
    #pragma unroll
    for (int k = 0; k < 4; k++) {
        int v = flags[base + k] & 1;
        ull key = v ? minkey[base + k] : inv;
        int m = (key < thr_key) && v;
        int u = (!m) && v;
        iv[k] = (int)(key & 0xffffffffULL);
        um[k] = u; usum += u; msum += m;
        flags[base + k] = v | (m << 1) | (u << 2);
    }
    su[t] = usum; smc[t] = msum;
    __syncthreads();
    for (int off = 1; off < 1024; off <<= 1) {
        int a = su[t], b = (t >= off) ? su[t - off] : 0;
        int c = smc[t], d = (t >= off) ? smc[t - off] : 0;
        __syncthreads();
        su[t] = a + b; smc[t] = c + d;
        __syncthreads();
    }
    int excl = su[t] - usum;
    int np_ = *next_ptr;
    int run = excl;
    #pragma unroll
    for (int k = 0; k < 4; k++) {
        int wv;
        if (um[k]) { run += 1; wv = (np_ + run - 1) % N_MEM; }
        else       { wv = iv[k]; }
        widx[base + k] = wv;
        wvv[k] = wv;
        winner[wv] = -1;                   // init touched slots (racing -1 stores benign)
    }
    __syncthreads();
    #pragma unroll
    for (int k = 0; k < 4; k++)
        atomicMax(&winner[wvv[k]], base + k);   // last-write-wins = max p per slot
    if (t == 1023) {
        dout[1]     = (float)smc[1023];                 // n_match
        scan_out[0] = (float)(smc[1023] + su[1023]);    // nv = matched + unmatched valid
        scan_out[1] = (float)su[1023];                  // n_unmatched valid (each cos=1)
    }
}

// ---------------- D4: scatter + matched-cos accumulation (NO fence, NO election) -------
// sum(cos*valid) = sum_matched(cosv) + n_unmatched. Matched blocks atomicAdd cosv
// (~few hundred low-contention adds); loss finalized by tiny k_final.
__global__ __launch_bounds__(256) void k_scatloss(const int* __restrict__ widx,
                                                  const int* __restrict__ flags,
                                                  const int* __restrict__ winner,
                                                  const float* __restrict__ desc,
                                                  const float4* __restrict__ pts,
                                                  const float* __restrict__ mem_pts,
                                                  const float* __restrict__ mem_desc,
                                                  float* __restrict__ out_pts,
                                                  float* __restrict__ out_desc,
                                                  float* __restrict__ cos_acc)
{
    __shared__ float red[16];
    int p = blockIdx.x;
    int t = threadIdx.x;
    int f = flags[p];
    int m = (f >> 1) & 1, u = (f >> 2) & 1;
    int wi = widx[p];
    int win = (winner[wi] == p);
    if (!m && !win) return;                 // block-uniform early exit: nothing to do
    float dsg = desc[p * DDIM + t];
    float old = mem_desc[(long)wi * DDIM + t];   // for matched, wi == idx[p]
    float val;
    if (m) {
        float up = old * 0.5f + dsg * 0.5f;
        float sdd = dsg * dsg, smm2 = old * old, sdm = dsg * old, suu = up * up;
        for (int off = 32; off; off >>= 1) {
            sdd  += __shfl_xor(sdd,  off);
            smm2 += __shfl_xor(smm2, off);
            sdm  += __shfl_xor(sdm,  off);
            suu  += __shfl_xor(suu,  off);
        }
        int w = t >> 6;
        if ((t & 63) == 0) { red[w] = sdd; red[4+w] = smm2; red[8+w] = sdm; red[12+w] = suu; }
        __syncthreads();
        float dd  = red[0] + red[1] + red[2] + red[3];
        float mm2 = red[4] + red[5] + red[6] + red[7];
        float dm  = red[8] + red[9] + red[10] + red[11];
        float uu  = red[12] + red[13] + red[14] + red[15];
        float cosv = dm / (fmaxf(sqrtf(dd), EPSF) * fmaxf(sqrtf(mm2), EPSF));
        val = up / (sqrtf(uu) + EPSF);
        if (t == 0) atomicAdd(cos_acc, cosv);   // matched contribution (win or not)
    } else {
        val = u ? dsg : old;                // invalid winner rewrites old value (np semantics)
    }
    if (win) {
        out_desc[(long)wi * DDIM + t] = val;
        if (t == 0) {
            float px, py, pz;
            if (u) { float4 P = pts[p]; px = P.x; py = P.y; pz = P.z; }
            else   { px = mem_pts[wi*3]; py = mem_pts[wi*3+1]; pz = mem_pts[wi*3+2]; }
            out_pts[wi*3+0] = px; out_pts[wi*3+1] = py; out_pts[wi*3+2] = pz;
        }
    }
}

// ---------------- D5: O(1) loss finalize ----------------
__global__ void k_final(const float* __restrict__ cos_acc,
                        const float* __restrict__ scan_out,
                        float* __restrict__ dout)
{
    if (threadIdx.x == 0) {
        float nv = fmaxf(scan_out[0], 1.f);
        dout[0] = 1.f - (*cos_acc + scan_out[1]) / nv;
    }
}

extern "C" void kernel_launch(void* const* d_in, const int* in_sizes, int n_in,
                              void* d_out, int out_size, void* d_ws, size_t ws_size,
                              hipStream_t stream)
{
    const float* points   = (const float*)d_in[0];
    const float* depth    = (const float*)d_in[1];
    const float* pose     = (const float*)d_in[2];
    const float* Kmat     = (const float*)d_in[3];
    const float* desc     = (const float*)d_in[4];
    const float* mem_pts  = (const float*)d_in[5];
    const float* mem_desc = (const float*)d_in[6];
    const int*   next_ptr = (const int*)d_in[7];

    float* out      = (float*)d_out;
    float* out_pts  = out + 2;
    float* out_desc = out + 2 + (long)N_MEM * 3;

    char* ws = (char*)d_ws;
    float4* pts_ws    = (float4*)(ws);               //  65536 B
    int* flags_ws     = (int*)(ws + 65536);          //  16384 -> 81920
    int* widx_ws      = (int*)(ws + 81920);          //  16384 -> 98304
    int* winner_ws    = (int*)(ws + 98304);          // 200000 -> 298304
    ull* minkey_ws    = (ull*)(ws + 298304);         //  32768 -> 331072 (8B aligned)
    int* qstart_ws    = (int*)(ws + 331072);         //  55300 -> 386372
    int* qidx_ws      = (int*)(ws + 386372);         //  16384 -> 402756
    ull* minkey_inv   = (ull*)(ws + 402760);         //      8 -> 402768 (8B aligned)
    float* scan_out   = (float*)(ws + 402768);       //      8 -> 402776
    float* cos_acc    = (float*)(ws + 402776);       //      4 -> 402780

    k_build   <<<1, 1024, 0, stream>>>(points, depth, pose, Kmat,
                                       pts_ws, flags_ws, minkey_ws,
                                       qstart_ws, qidx_ws, minkey_inv, cos_acc);
    k_main    <<<SWEEPB + COPYB, 256, 0, stream>>>(mem_pts, mem_desc, pts_ws,
                                                   qstart_ws, qidx_ws, minkey_ws, minkey_inv,
                                                   out_pts, out_desc);
    k_scan    <<<1, 1024, 0, stream>>>(minkey_ws, flags_ws, next_ptr, minkey_inv,
                                       widx_ws, winner_ws, out, scan_out);
    k_scatloss<<<P_TOT, 256, 0, stream>>>(widx_ws, flags_ws, winner_ws, desc, pts_ws,
                                          mem_pts, mem_desc, out_pts, out_desc, cos_acc);
    k_final   <<<1, 64, 0, stream>>>(cos_acc, scan_out, out);
}